// Round 20
// baseline (49.686 us; speedup 1.0000x reference)
//
#include <hip/hip_runtime.h>

// TreeGCN fused kernels for MI355X (gfx950) — R19.
// B=64, NODES=512, DEG=8, IN_F=64, OUT_F=64, SUP=640.
// WsF = Ws1@Ws2 precomputed (no nonlinearity between).
// R19 = R17 (best: 43.9; plain loads/stores, XCD swizzle) restructured as a
// 2-deep intra-block pipeline: block = n, brB double-buffered; dh1's global
// loads are issued into registers BEFORE dh0's compute so reads overlap
// compute+store issue, and dh0's writeback drains under dh1's compute.
// NT rejected both ways (R15: loads cold-refetch; R18: store amplification).

typedef float f32x4 __attribute__((ext_vector_type(4)));
typedef __bf16 bf16x8 __attribute__((ext_vector_type(8)));

__device__ __forceinline__ unsigned short f2bf(float f) {
    union { float f; unsigned int u; } x; x.f = f;
    unsigned int r = x.u + 0x7FFFu + ((x.u >> 16) & 1u);
    return (unsigned short)(r >> 16);
}

// ---------------- prep: ylg + xbf + wsF + w3f (R17, unchanged) ---------------
// grid 1601 x 256: [0,1024) ylg; [1024,1536) xbf; [1536,1600) wsF; 1600 w3f
__global__ __launch_bounds__(256) void tree_prep(
    const float* __restrict__ x0, const float* __restrict__ W0,
    const float* __restrict__ x1, const float* __restrict__ W1,
    const float* __restrict__ x2, const float* __restrict__ W2,
    const float* __restrict__ x3, const float* __restrict__ W3,
    const float* __restrict__ Ws1, const float* __restrict__ Ws2,
    float* __restrict__ ylg, unsigned short* __restrict__ xbf,
    unsigned short* __restrict__ wsF, unsigned short* __restrict__ w3f)
{
    const int t = threadIdx.x;
    const int blk = blockIdx.x;
    if (blk < 1024) {
        __shared__ float red[4][64];
        const int b = blk >> 4, q = blk & 15;
        const int f = t & 63, kq = t >> 6;
        float p0 = 0.f, p1 = 0.f;
        const float* x0p = x0 + b * 96 + kq * 24;
        #pragma unroll 6
        for (int k = 0; k < 24; k += 2) {
            p0 += x0p[k]     * W0[(kq * 24 + k) * 64 + f];
            p1 += x0p[k + 1] * W0[(kq * 24 + k + 1) * 64 + f];
        }
        const int oct = q >> 1;
        const float* x1p = x1 + b * 512 + oct * 64 + kq * 16;
        #pragma unroll 8
        for (int k = 0; k < 16; k += 2) {
            p0 += x1p[k]     * W1[(kq * 16 + k) * 64 + f];
            p1 += x1p[k + 1] * W1[(kq * 16 + k + 1) * 64 + f];
        }
        red[kq][f] = p0 + p1;
        __syncthreads();
        const int gl = t >> 6;
        const int g = q * 4 + gl;
        float acc = red[0][f] + red[1][f] + red[2][f] + red[3][f];
        const float* x2p = x2 + (size_t)b * 4096 + g * 64;
        float c0 = 0.f, c1 = 0.f;
        #pragma unroll 8
        for (int k = 0; k < 64; k += 2) {
            c0 += x2p[k]     * W2[k * 64 + f];
            c1 += x2p[k + 1] * W2[(k + 1) * 64 + f];
        }
        acc += c0 + c1;
        const int mt = b >> 4, l4m = (b >> 2) & 3, rm = b & 3;
        const int ft = f >> 4, l15 = f & 15;
        ylg[(size_t)((g * 4 + mt) * 4 + ft) * 256 + (l4m * 16 + l15) * 4 + rm] = acc;
    } else if (blk < 1536) {
        const int bb = blk - 1024;
        const int b = bb >> 3, q = bb & 7;
        const int n = q * 64 + (t >> 2), kq = t & 3;
        const int mt = b >> 4, l15b = b & 15;
        const float* src = x3 + (size_t)b * 32768 + (size_t)n * 64 + kq * 16;
        #pragma unroll
        for (int i = 0; i < 4; ++i) {
            float4 v = *(const float4*)(src + 4 * i);
            const int k0 = kq * 16 + 4 * i;
            const int ks = k0 >> 5, l4k = (k0 >> 3) & 3, j = k0 & 7;
            union { unsigned short h[4]; uint2 u; } p;
            p.h[0] = f2bf(v.x); p.h[1] = f2bf(v.y); p.h[2] = f2bf(v.z); p.h[3] = f2bf(v.w);
            *(uint2*)&xbf[(size_t)n * 4096 +
                          ((mt * 2 + ks) * 64 + l4k * 16 + l15b) * 8 + j] = p.u;
        }
    } else if (blk < 1600) {
        __shared__ float red[4][64];
        const int c = blk - 1536;
        const int f = t & 63, q = t >> 6;
        const float* w1p = Ws1 + (size_t)c * 640 + q * 160;
        const float* w2p = Ws2 + (size_t)(q * 160) * 64 + f;
        float a0 = 0.f, a1 = 0.f;
        #pragma unroll 8
        for (int s = 0; s < 160; s += 2) {
            a0 += w1p[s]     * w2p[(size_t)s * 64];
            a1 += w1p[s + 1] * w2p[(size_t)(s + 1) * 64];
        }
        red[q][f] = a0 + a1;
        __syncthreads();
        if (q == 0) {
            const float v = red[0][f] + red[1][f] + red[2][f] + red[3][f];
            const int ks = c >> 5, l4c = (c >> 3) & 3, j = c & 7;
            wsF[((f >> 4) * 2 + ks) * 512 + (l4c * 16 + (f & 15)) * 8 + j] = f2bf(v);
        }
    } else {
        const int l = t & 63;
        #pragma unroll
        for (int it = 0; it < 2; ++it) {
            const int fh = it * 4 + (t >> 6);
            const int ft = fh >> 1, ks = fh & 1;
            const int f = ft * 16 + (l & 15);
            const int kb = ks * 32 + (l >> 4) * 8;
            union { unsigned short h[8]; uint4 u; } p;
            #pragma unroll
            for (int j = 0; j < 8; ++j) p.h[j] = f2bf(W3[(kb + j) * 64 + f]);
            *(uint4*)&w3f[((size_t)fh * 64 + l) * 8] = p.u;
        }
    }
}

// ---------------- main: block = n (XCD-swizzled); 2-deep dh pipeline ---------
// grid 512 x 256; LDS 73.5 KB -> 2 blocks/CU; wave w -> d = 4*dh + w
__global__ __launch_bounds__(256, 2) void tree_main(
    const float* __restrict__ branch, const float* __restrict__ bias,
    const float* __restrict__ ylg, const unsigned short* __restrict__ xbf,
    const unsigned short* __restrict__ wsF, const unsigned short* __restrict__ w3f,
    float* __restrict__ out)
{
    __shared__ unsigned short brB[2][64 * 258];  // 2 x 33 KB dbuf (dh halves)
    __shared__ unsigned short tsb[4][16 * 72];   // per-wave Ts
    const int t = threadIdx.x;
    const int w = t >> 6, l = t & 63;
    const int l15 = l & 15, l4 = l >> 4;
    // bijective XCD swizzle (512 % 8 == 0): contiguous 64-node slab per XCD
    const int n = (blockIdx.x & 7) * 64 + (blockIdx.x >> 3);
    const int g = n >> 3;
    unsigned short* ts = tsb[w];

    // ---- X frags (L2-resident in this XCD's slab)
    bf16x8 bx[4][2];
    #pragma unroll
    for (int bt = 0; bt < 4; ++bt)
        #pragma unroll
        for (int ks = 0; ks < 2; ++ks)
            bx[bt][ks] = *(const bf16x8*)(xbf + (size_t)n * 4096 +
                                          ((bt * 2 + ks) * 64 + l) * 8);

    // ---- stage dh0 half -> brB[0]
    {
        const float* bp = branch + (size_t)n * 32768;
        f32x4 stg[16];
        #pragma unroll
        for (int i = 0; i < 16; ++i) {
            const int fi = i * 256 + t;
            const int k = fi >> 6, c4 = (fi & 63) << 2;
            stg[i] = *(const f32x4*)(bp + (size_t)k * 512 + c4);
        }
        #pragma unroll
        for (int i = 0; i < 16; ++i) {
            const int fi = i * 256 + t;
            const int k = fi >> 6, c4 = (fi & 63) << 2;
            union { unsigned short h[4]; uint2 u; } q;
            q.h[0] = f2bf(stg[i][0]); q.h[1] = f2bf(stg[i][1]);
            q.h[2] = f2bf(stg[i][2]); q.h[3] = f2bf(stg[i][3]);
            *(uint2*)&brB[0][k * 258 + c4] = q.u;
        }
    }
    __syncthreads();

    // ---- issue dh1 loads EARLY (stay in flight across dh0 compute+stores)
    f32x4 stg1[16];
    {
        const float* bp = branch + (size_t)n * 32768 + 256;
        #pragma unroll
        for (int i = 0; i < 16; ++i) {
            const int fi = i * 256 + t;
            const int k = fi >> 6, c4 = (fi & 63) << 2;
            stg1[i] = *(const f32x4*)(bp + (size_t)k * 512 + c4);
        }
    }

    // ---- compute one dh half: pf extract -> per-bt GEMM1 -> Ts -> GEMM2 -> store
    auto compute = [&](const unsigned short* br, const int d) {
        bf16x8 pf[4][2];
        #pragma unroll
        for (int cP = 0; cP < 4; ++cP)
            #pragma unroll
            for (int ks = 0; ks < 2; ++ks) {
                union { unsigned short h[8]; bf16x8 bv; } p;
                #pragma unroll
                for (int j = 0; j < 8; ++j)
                    p.h[j] = br[(32 * ks + 8 * l4 + j) * 258 + w * 64 + 16 * cP + l15];
                pf[cP][ks] = p.bv;
            }
        float* outp = out + (size_t)(n * 8 + d) * 64;
        #pragma unroll
        for (int bt = 0; bt < 4; ++bt) {
            #pragma unroll
            for (int cP = 0; cP < 4; ++cP) {
                f32x4 s = {0.f, 0.f, 0.f, 0.f};
                s = __builtin_amdgcn_mfma_f32_16x16x32_bf16(pf[cP][0], bx[bt][0], s, 0, 0, 0);
                s = __builtin_amdgcn_mfma_f32_16x16x32_bf16(pf[cP][1], bx[bt][1], s, 0, 0, 0);
                union { unsigned short h[4]; uint2 u; } q;
                #pragma unroll
                for (int r = 0; r < 4; ++r) {
                    float v = s[r];
                    v = fmaxf(v, 0.2f * v);
                    q.h[r] = f2bf(v);
                }
                *(uint2*)&ts[l15 * 72 + 16 * cP + 4 * l4] = q.u;
            }
            bf16x8 a20 = *(const bf16x8*)&ts[l15 * 72 + 8 * l4];
            bf16x8 a21 = *(const bf16x8*)&ts[l15 * 72 + 32 + 8 * l4];
            #pragma unroll
            for (int ft = 0; ft < 4; ++ft) {
                f32x4 o = *(const f32x4*)(ylg + (size_t)((g * 4 + bt) * 4 + ft) * 256 + l * 4);
                bf16x8 w30 = *(const bf16x8*)(w3f + (size_t)((ft * 2 + 0) * 64 + l) * 8);
                bf16x8 w31 = *(const bf16x8*)(w3f + (size_t)((ft * 2 + 1) * 64 + l) * 8);
                bf16x8 wf0 = *(const bf16x8*)(wsF + (size_t)((ft * 2 + 0) * 64 + l) * 8);
                bf16x8 wf1 = *(const bf16x8*)(wsF + (size_t)((ft * 2 + 1) * 64 + l) * 8);
                o = __builtin_amdgcn_mfma_f32_16x16x32_bf16(bx[bt][0], w30, o, 0, 0, 0);
                o = __builtin_amdgcn_mfma_f32_16x16x32_bf16(bx[bt][1], w31, o, 0, 0, 0);
                o = __builtin_amdgcn_mfma_f32_16x16x32_bf16(a20, wf0, o, 0, 0, 0);
                o = __builtin_amdgcn_mfma_f32_16x16x32_bf16(a21, wf1, o, 0, 0, 0);
                const float bv = bias[d * 64 + 16 * ft + l15];
                #pragma unroll
                for (int r = 0; r < 4; ++r) {
                    float val = o[r] + bv;
                    val = fmaxf(val, 0.2f * val);
                    outp[(size_t)(16 * bt + 4 * l4 + r) * 262144 + 16 * ft + l15] = val;
                }
            }
        }
    };

    compute(brB[0], w);           // d = w; dh1 loads + dh0 writebacks in flight

    // ---- write dh1 half -> brB[1] (vmcnt wait lands here)
    {
        #pragma unroll
        for (int i = 0; i < 16; ++i) {
            const int fi = i * 256 + t;
            const int k = fi >> 6, c4 = (fi & 63) << 2;
            union { unsigned short h[4]; uint2 u; } q;
            q.h[0] = f2bf(stg1[i][0]); q.h[1] = f2bf(stg1[i][1]);
            q.h[2] = f2bf(stg1[i][2]); q.h[3] = f2bf(stg1[i][3]);
            *(uint2*)&brB[1][k * 258 + c4] = q.u;
        }
    }
    __syncthreads();

    compute(brB[1], 4 + w);       // d = 4 + w; dh0 writebacks drain underneath
}

extern "C" void kernel_launch(void* const* d_in, const int* in_sizes, int n_in,
                              void* d_out, int out_size, void* d_ws, size_t ws_size,
                              hipStream_t stream) {
    (void)in_sizes; (void)n_in; (void)out_size; (void)ws_size;
    const float* x0     = (const float*)d_in[0];
    const float* W0     = (const float*)d_in[1];
    const float* x1     = (const float*)d_in[2];
    const float* W1     = (const float*)d_in[3];
    const float* x2     = (const float*)d_in[4];
    const float* W2     = (const float*)d_in[5];
    const float* x3     = (const float*)d_in[6];
    const float* W3     = (const float*)d_in[7];
    const float* branch = (const float*)d_in[8];
    const float* Ws1    = (const float*)d_in[9];
    const float* Ws2    = (const float*)d_in[10];
    const float* bias   = (const float*)d_in[11];

    float* ylg          = (float*)d_ws;                                   // 1 MiB
    unsigned short* xbf = (unsigned short*)((char*)d_ws + 1048576);       // 4 MiB
    unsigned short* wsF = (unsigned short*)((char*)d_ws + 5242880);       // 8 KiB
    unsigned short* w3f = (unsigned short*)((char*)d_ws + 5251072);       // 8 KiB
    float* out = (float*)d_out;

    tree_prep<<<1601, 256, 0, stream>>>(x0, W0, x1, W1, x2, W2, x3, W3, Ws1, Ws2,
                                        ylg, xbf, wsF, w3f);
    tree_main<<<512, 256, 0, stream>>>(branch, bias, ylg, xbf, wsF, w3f, out);
}

// Round 21
// 44.029 us; speedup vs baseline: 1.1285x; 1.1285x over previous
//
#include <hip/hip_runtime.h>

// TreeGCN fused kernels for MI355X (gfx950) — R20 (= R17, the measured best).
// B=64, NODES=512, DEG=8, IN_F=64, OUT_F=64, SUP=640.
// WsF = Ws1@Ws2 precomputed (no nonlinearity between).
// R17 config: plain loads/stores (NT rejected both ways: R15 loads
// cold-refetch, R18 stores amplify), XCD-swizzled (n,dh) blocks, 33KB LDS
// (Ts aliases brB) -> 4 blocks/CU, short-chain prep. Measured 43.9us.
// R19's 2-deep pipeline reverted (spill + occupancy loss, 49.7us).

typedef float f32x4 __attribute__((ext_vector_type(4)));
typedef __bf16 bf16x8 __attribute__((ext_vector_type(8)));

__device__ __forceinline__ unsigned short f2bf(float f) {
    union { float f; unsigned int u; } x; x.f = f;
    unsigned int r = x.u + 0x7FFFu + ((x.u >> 16) & 1u);
    return (unsigned short)(r >> 16);
}

// ---------------- prep: ylg + xbf + wsF + w3f --------------------------------
// grid 1601 x 256: [0,1024) ylg; [1024,1536) xbf; [1536,1600) wsF; 1600 w3f
__global__ __launch_bounds__(256) void tree_prep(
    const float* __restrict__ x0, const float* __restrict__ W0,
    const float* __restrict__ x1, const float* __restrict__ W1,
    const float* __restrict__ x2, const float* __restrict__ W2,
    const float* __restrict__ x3, const float* __restrict__ W3,
    const float* __restrict__ Ws1, const float* __restrict__ Ws2,
    float* __restrict__ ylg, unsigned short* __restrict__ xbf,
    unsigned short* __restrict__ wsF, unsigned short* __restrict__ w3f)
{
    const int t = threadIdx.x;
    const int blk = blockIdx.x;
    if (blk < 1024) {
        // ylg for b = blk>>4, g-quad q = blk&15 (g = 4q+gl, all same oct q>>1)
        __shared__ float red[4][64];
        const int b = blk >> 4, q = blk & 15;
        const int f = t & 63, kq = t >> 6;
        // phase 1: cooperative a01[f] = (x0@W0)[b,f] + (x1@W1)[b,oct,f], k 4-way
        float p0 = 0.f, p1 = 0.f;
        const float* x0p = x0 + b * 96 + kq * 24;
        #pragma unroll 6
        for (int k = 0; k < 24; k += 2) {
            p0 += x0p[k]     * W0[(kq * 24 + k) * 64 + f];
            p1 += x0p[k + 1] * W0[(kq * 24 + k + 1) * 64 + f];
        }
        const int oct = q >> 1;
        const float* x1p = x1 + b * 512 + oct * 64 + kq * 16;
        #pragma unroll 8
        for (int k = 0; k < 16; k += 2) {
            p0 += x1p[k]     * W1[(kq * 16 + k) * 64 + f];
            p1 += x1p[k + 1] * W1[(kq * 16 + k + 1) * 64 + f];
        }
        red[kq][f] = p0 + p1;
        __syncthreads();
        // phase 2: one output per thread: + (x2@W2)[b,g,f]
        const int gl = t >> 6;
        const int g = q * 4 + gl;
        float acc = red[0][f] + red[1][f] + red[2][f] + red[3][f];
        const float* x2p = x2 + (size_t)b * 4096 + g * 64;
        float c0 = 0.f, c1 = 0.f;
        #pragma unroll 8
        for (int k = 0; k < 64; k += 2) {
            c0 += x2p[k]     * W2[k * 64 + f];
            c1 += x2p[k + 1] * W2[(k + 1) * 64 + f];
        }
        acc += c0 + c1;
        const int mt = b >> 4, l4m = (b >> 2) & 3, rm = b & 3;
        const int ft = f >> 4, l15 = f & 15;
        ylg[(size_t)((g * 4 + mt) * 4 + ft) * 256 + (l4m * 16 + l15) * 4 + rm] = acc;
    } else if (blk < 1536) {
        // xbf frags: b = bb>>3, n-range q*64..+64; thread does 4 float4
        const int bb = blk - 1024;
        const int b = bb >> 3, q = bb & 7;
        const int n = q * 64 + (t >> 2), kq = t & 3;
        const int mt = b >> 4, l15b = b & 15;
        const float* src = x3 + (size_t)b * 32768 + (size_t)n * 64 + kq * 16;
        #pragma unroll
        for (int i = 0; i < 4; ++i) {
            float4 v = *(const float4*)(src + 4 * i);
            const int k0 = kq * 16 + 4 * i;
            const int ks = k0 >> 5, l4k = (k0 >> 3) & 3, j = k0 & 7;
            union { unsigned short h[4]; uint2 u; } p;
            p.h[0] = f2bf(v.x); p.h[1] = f2bf(v.y); p.h[2] = f2bf(v.z); p.h[3] = f2bf(v.w);
            *(uint2*)&xbf[(size_t)n * 4096 +
                          ((mt * 2 + ks) * 64 + l4k * 16 + l15b) * 8 + j] = p.u;
        }
    } else if (blk < 1600) {
        // wsF B-frags: value (Ws1@Ws2)[c][f]; block = one c, s split 4-way
        __shared__ float red[4][64];
        const int c = blk - 1536;
        const int f = t & 63, q = t >> 6;
        const float* w1p = Ws1 + (size_t)c * 640 + q * 160;
        const float* w2p = Ws2 + (size_t)(q * 160) * 64 + f;
        float a0 = 0.f, a1 = 0.f;
        #pragma unroll 8
        for (int s = 0; s < 160; s += 2) {
            a0 += w1p[s]     * w2p[(size_t)s * 64];
            a1 += w1p[s + 1] * w2p[(size_t)(s + 1) * 64];
        }
        red[q][f] = a0 + a1;
        __syncthreads();
        if (q == 0) {
            const float v = red[0][f] + red[1][f] + red[2][f] + red[3][f];
            const int ks = c >> 5, l4c = (c >> 3) & 3, j = c & 7;
            wsF[((f >> 4) * 2 + ks) * 512 + (l4c * 16 + (f & 15)) * 8 + j] = f2bf(v);
        }
    } else {
        // w3f B-frags: value W3[k][f]
        const int l = t & 63;
        #pragma unroll
        for (int it = 0; it < 2; ++it) {
            const int fh = it * 4 + (t >> 6);
            const int ft = fh >> 1, ks = fh & 1;
            const int f = ft * 16 + (l & 15);
            const int kb = ks * 32 + (l >> 4) * 8;
            union { unsigned short h[8]; uint4 u; } p;
            #pragma unroll
            for (int j = 0; j < 8; ++j) p.h[j] = f2bf(W3[(kb + j) * 64 + f]);
            *(uint4*)&w3f[((size_t)fh * 64 + l) * 8] = p.u;
        }
    }
}

// ---------------- main: block = (n, dh) via XCD swizzle; wave -> d -----------
// grid 1024 x 256; 33 KB LDS (Ts aliases brB) -> 4 blocks/CU
__global__ __launch_bounds__(256, 4) void tree_main(
    const float* __restrict__ branch, const float* __restrict__ bias,
    const float* __restrict__ ylg, const unsigned short* __restrict__ xbf,
    const unsigned short* __restrict__ wsF, const unsigned short* __restrict__ w3f,
    float* __restrict__ out)
{
    __shared__ unsigned short mem[64 * 258];   // 33 KB: brB [k][c-half]; Ts aliased
    const int t = threadIdx.x;
    const int w = t >> 6, l = t & 63;
    const int l15 = l & 15, l4 = l >> 4;
    // bijective XCD swizzle (1024 % 8 == 0): each XCD gets a contiguous
    // 64-node slab -> xbf/ylg slices stay in its private L2.
    const int blk = (blockIdx.x & 7) * 128 + (blockIdx.x >> 3);
    const int n = blk >> 1, dh = blk & 1;
    const int d = 4 * dh + w;
    const int g = n >> 3;

    // ---- X frags (issued first; L2-resident in this XCD's slab)
    bf16x8 bx[4][2];
    #pragma unroll
    for (int bt = 0; bt < 4; ++bt)
        #pragma unroll
        for (int ks = 0; ks < 2; ++ks)
            bx[bt][ks] = *(const bf16x8*)(xbf + (size_t)n * 4096 +
                                          ((bt * 2 + ks) * 64 + l) * 8);

    // ---- stage branch[n][k][dh*256 .. +256): fp32 -> bf16 LDS (plain loads)
    {
        const float* bp = branch + (size_t)n * 32768 + dh * 256;
        #pragma unroll
        for (int half = 0; half < 2; ++half) {
            f32x4 stg[8];
            #pragma unroll
            for (int i = 0; i < 8; ++i) {
                const int fi = (half * 8 + i) * 256 + t;
                const int k = fi >> 6, c4 = (fi & 63) << 2;
                stg[i] = *(const f32x4*)(bp + (size_t)k * 512 + c4);
            }
            #pragma unroll
            for (int i = 0; i < 8; ++i) {
                const int fi = (half * 8 + i) * 256 + t;
                const int k = fi >> 6, c4 = (fi & 63) << 2;
                union { unsigned short h[4]; uint2 u; } q;
                q.h[0] = f2bf(stg[i][0]); q.h[1] = f2bf(stg[i][1]);
                q.h[2] = f2bf(stg[i][2]); q.h[3] = f2bf(stg[i][3]);
                *(uint2*)&mem[k * 258 + c4] = q.u;
            }
        }
    }
    __syncthreads();

    // ---- pf: A-frags of S^T = Br[k][w*64+c] (129-word stride: conflict-free)
    bf16x8 pf[4][2];
    #pragma unroll
    for (int cP = 0; cP < 4; ++cP)
        #pragma unroll
        for (int ks = 0; ks < 2; ++ks) {
            union { unsigned short h[8]; bf16x8 bv; } p;
            #pragma unroll
            for (int j = 0; j < 8; ++j)
                p.h[j] = mem[(32 * ks + 8 * l4 + j) * 258 + w * 64 + 16 * cP + l15];
            pf[cP][ks] = p.bv;
        }
    __syncthreads();  // brB dead; Ts may now overwrite it

    unsigned short* ts = mem + w * (16 * 72);

    // ---- per-bt: GEMM1^T -> Ts -> (ylg + X@W3 + T@WsF) -> store
    float* outp = out + (size_t)(n * 8 + d) * 64;
    #pragma unroll
    for (int bt = 0; bt < 4; ++bt) {
        #pragma unroll
        for (int cP = 0; cP < 4; ++cP) {
            f32x4 s = {0.f, 0.f, 0.f, 0.f};
            s = __builtin_amdgcn_mfma_f32_16x16x32_bf16(pf[cP][0], bx[bt][0], s, 0, 0, 0);
            s = __builtin_amdgcn_mfma_f32_16x16x32_bf16(pf[cP][1], bx[bt][1], s, 0, 0, 0);
            union { unsigned short h[4]; uint2 u; } q;
            #pragma unroll
            for (int r = 0; r < 4; ++r) {
                float v = s[r];
                v = fmaxf(v, 0.2f * v);
                q.h[r] = f2bf(v);
            }
            *(uint2*)&ts[l15 * 72 + 16 * cP + 4 * l4] = q.u;
        }
        bf16x8 a20 = *(const bf16x8*)&ts[l15 * 72 + 8 * l4];
        bf16x8 a21 = *(const bf16x8*)&ts[l15 * 72 + 32 + 8 * l4];
        #pragma unroll
        for (int ft = 0; ft < 4; ++ft) {
            f32x4 o = *(const f32x4*)(ylg + (size_t)((g * 4 + bt) * 4 + ft) * 256 + l * 4);
            bf16x8 w30 = *(const bf16x8*)(w3f + (size_t)((ft * 2 + 0) * 64 + l) * 8);
            bf16x8 w31 = *(const bf16x8*)(w3f + (size_t)((ft * 2 + 1) * 64 + l) * 8);
            bf16x8 wf0 = *(const bf16x8*)(wsF + (size_t)((ft * 2 + 0) * 64 + l) * 8);
            bf16x8 wf1 = *(const bf16x8*)(wsF + (size_t)((ft * 2 + 1) * 64 + l) * 8);
            o = __builtin_amdgcn_mfma_f32_16x16x32_bf16(bx[bt][0], w30, o, 0, 0, 0);
            o = __builtin_amdgcn_mfma_f32_16x16x32_bf16(bx[bt][1], w31, o, 0, 0, 0);
            o = __builtin_amdgcn_mfma_f32_16x16x32_bf16(a20, wf0, o, 0, 0, 0);
            o = __builtin_amdgcn_mfma_f32_16x16x32_bf16(a21, wf1, o, 0, 0, 0);
            const float bv = bias[d * 64 + 16 * ft + l15];
            #pragma unroll
            for (int r = 0; r < 4; ++r) {
                float val = o[r] + bv;
                val = fmaxf(val, 0.2f * val);
                outp[(size_t)(16 * bt + 4 * l4 + r) * 262144 + 16 * ft + l15] = val;
            }
        }
    }
}

extern "C" void kernel_launch(void* const* d_in, const int* in_sizes, int n_in,
                              void* d_out, int out_size, void* d_ws, size_t ws_size,
                              hipStream_t stream) {
    (void)in_sizes; (void)n_in; (void)out_size; (void)ws_size;
    const float* x0     = (const float*)d_in[0];
    const float* W0     = (const float*)d_in[1];
    const float* x1     = (const float*)d_in[2];
    const float* W1     = (const float*)d_in[3];
    const float* x2     = (const float*)d_in[4];
    const float* W2     = (const float*)d_in[5];
    const float* x3     = (const float*)d_in[6];
    const float* W3     = (const float*)d_in[7];
    const float* branch = (const float*)d_in[8];
    const float* Ws1    = (const float*)d_in[9];
    const float* Ws2    = (const float*)d_in[10];
    const float* bias   = (const float*)d_in[11];

    float* ylg          = (float*)d_ws;                                   // 1 MiB
    unsigned short* xbf = (unsigned short*)((char*)d_ws + 1048576);       // 4 MiB
    unsigned short* wsF = (unsigned short*)((char*)d_ws + 5242880);       // 8 KiB
    unsigned short* w3f = (unsigned short*)((char*)d_ws + 5251072);       // 8 KiB
    float* out = (float*)d_out;

    tree_prep<<<1601, 256, 0, stream>>>(x0, W0, x1, W1, x2, W2, x3, W3, Ws1, Ws2,
                                        ylg, xbf, wsF, w3f);
    tree_main<<<1024, 256, 0, stream>>>(branch, bias, ylg, xbf, wsF, w3f, out);
}

// Round 22
// 43.668 us; speedup vs baseline: 1.1378x; 1.0083x over previous
//
#include <hip/hip_runtime.h>

// TreeGCN fused kernels for MI355X (gfx950) — R21.
// B=64, NODES=512, DEG=8, IN_F=64, OUT_F=64, SUP=640.
// WsF = Ws1@Ws2 precomputed (no nonlinearity between).
// R21 = R17 math with TWO-GENERATION launch: block = (n, d), grid 4096,
// 17.5 KB LDS -> 8 blocks/CU resident, 16 total/CU. Gen-2 read bursts
// overlap gen-1 writeback drains (every prior schedule was 1 generation =
// globally phase-locked stage/compute/drain). Wave w owns bt=w; XCD swizzle
// keeps each XCD on a contiguous 64-node slab.

typedef float f32x4 __attribute__((ext_vector_type(4)));
typedef __bf16 bf16x8 __attribute__((ext_vector_type(8)));

__device__ __forceinline__ unsigned short f2bf(float f) {
    union { float f; unsigned int u; } x; x.f = f;
    unsigned int r = x.u + 0x7FFFu + ((x.u >> 16) & 1u);
    return (unsigned short)(r >> 16);
}

// ---------------- prep: ylg + xbf + wsF + w3f (R17, unchanged) ---------------
// grid 1601 x 256: [0,1024) ylg; [1024,1536) xbf; [1536,1600) wsF; 1600 w3f
__global__ __launch_bounds__(256) void tree_prep(
    const float* __restrict__ x0, const float* __restrict__ W0,
    const float* __restrict__ x1, const float* __restrict__ W1,
    const float* __restrict__ x2, const float* __restrict__ W2,
    const float* __restrict__ x3, const float* __restrict__ W3,
    const float* __restrict__ Ws1, const float* __restrict__ Ws2,
    float* __restrict__ ylg, unsigned short* __restrict__ xbf,
    unsigned short* __restrict__ wsF, unsigned short* __restrict__ w3f)
{
    const int t = threadIdx.x;
    const int blk = blockIdx.x;
    if (blk < 1024) {
        __shared__ float red[4][64];
        const int b = blk >> 4, q = blk & 15;
        const int f = t & 63, kq = t >> 6;
        float p0 = 0.f, p1 = 0.f;
        const float* x0p = x0 + b * 96 + kq * 24;
        #pragma unroll 6
        for (int k = 0; k < 24; k += 2) {
            p0 += x0p[k]     * W0[(kq * 24 + k) * 64 + f];
            p1 += x0p[k + 1] * W0[(kq * 24 + k + 1) * 64 + f];
        }
        const int oct = q >> 1;
        const float* x1p = x1 + b * 512 + oct * 64 + kq * 16;
        #pragma unroll 8
        for (int k = 0; k < 16; k += 2) {
            p0 += x1p[k]     * W1[(kq * 16 + k) * 64 + f];
            p1 += x1p[k + 1] * W1[(kq * 16 + k + 1) * 64 + f];
        }
        red[kq][f] = p0 + p1;
        __syncthreads();
        const int gl = t >> 6;
        const int g = q * 4 + gl;
        float acc = red[0][f] + red[1][f] + red[2][f] + red[3][f];
        const float* x2p = x2 + (size_t)b * 4096 + g * 64;
        float c0 = 0.f, c1 = 0.f;
        #pragma unroll 8
        for (int k = 0; k < 64; k += 2) {
            c0 += x2p[k]     * W2[k * 64 + f];
            c1 += x2p[k + 1] * W2[(k + 1) * 64 + f];
        }
        acc += c0 + c1;
        const int mt = b >> 4, l4m = (b >> 2) & 3, rm = b & 3;
        const int ft = f >> 4, l15 = f & 15;
        ylg[(size_t)((g * 4 + mt) * 4 + ft) * 256 + (l4m * 16 + l15) * 4 + rm] = acc;
    } else if (blk < 1536) {
        const int bb = blk - 1024;
        const int b = bb >> 3, q = bb & 7;
        const int n = q * 64 + (t >> 2), kq = t & 3;
        const int mt = b >> 4, l15b = b & 15;
        const float* src = x3 + (size_t)b * 32768 + (size_t)n * 64 + kq * 16;
        #pragma unroll
        for (int i = 0; i < 4; ++i) {
            float4 v = *(const float4*)(src + 4 * i);
            const int k0 = kq * 16 + 4 * i;
            const int ks = k0 >> 5, l4k = (k0 >> 3) & 3, j = k0 & 7;
            union { unsigned short h[4]; uint2 u; } p;
            p.h[0] = f2bf(v.x); p.h[1] = f2bf(v.y); p.h[2] = f2bf(v.z); p.h[3] = f2bf(v.w);
            *(uint2*)&xbf[(size_t)n * 4096 +
                          ((mt * 2 + ks) * 64 + l4k * 16 + l15b) * 8 + j] = p.u;
        }
    } else if (blk < 1600) {
        __shared__ float red[4][64];
        const int c = blk - 1536;
        const int f = t & 63, q = t >> 6;
        const float* w1p = Ws1 + (size_t)c * 640 + q * 160;
        const float* w2p = Ws2 + (size_t)(q * 160) * 64 + f;
        float a0 = 0.f, a1 = 0.f;
        #pragma unroll 8
        for (int s = 0; s < 160; s += 2) {
            a0 += w1p[s]     * w2p[(size_t)s * 64];
            a1 += w1p[s + 1] * w2p[(size_t)(s + 1) * 64];
        }
        red[q][f] = a0 + a1;
        __syncthreads();
        if (q == 0) {
            const float v = red[0][f] + red[1][f] + red[2][f] + red[3][f];
            const int ks = c >> 5, l4c = (c >> 3) & 3, j = c & 7;
            wsF[((f >> 4) * 2 + ks) * 512 + (l4c * 16 + (f & 15)) * 8 + j] = f2bf(v);
        }
    } else {
        const int l = t & 63;
        #pragma unroll
        for (int it = 0; it < 2; ++it) {
            const int fh = it * 4 + (t >> 6);
            const int ft = fh >> 1, ks = fh & 1;
            const int f = ft * 16 + (l & 15);
            const int kb = ks * 32 + (l >> 4) * 8;
            union { unsigned short h[8]; uint4 u; } p;
            #pragma unroll
            for (int j = 0; j < 8; ++j) p.h[j] = f2bf(W3[(kb + j) * 64 + f]);
            *(uint4*)&w3f[((size_t)fh * 64 + l) * 8] = p.u;
        }
    }
}

// ---------------- main: block = (n, d); 2 generations; wave w -> bt = w ------
// grid 4096 x 256; LDS 17.5 KB -> 8 blocks/CU resident (16 total/CU)
__global__ __launch_bounds__(256, 6) void tree_main(
    const float* __restrict__ branch, const float* __restrict__ bias,
    const float* __restrict__ ylg, const unsigned short* __restrict__ xbf,
    const unsigned short* __restrict__ wsF, const unsigned short* __restrict__ w3f,
    float* __restrict__ out)
{
    __shared__ unsigned short brB[64 * 68];     // 8.5 KB: bf16 [k][c(d-slice)], pad 4
    __shared__ unsigned short tsb[4][16 * 72];  // 9.2 KB: per-wave Ts
    const int t = threadIdx.x;
    const int w = t >> 6, l = t & 63;
    const int l15 = l & 15, l4 = l >> 4;
    // bijective XCD swizzle (4096 % 8 == 0): XCD x gets blk in [512x, 512(x+1))
    // -> n in [64x, 64(x+1)) contiguous slab (xbf/ylg L2-resident per XCD).
    const int blk = (blockIdx.x & 7) * 512 + (blockIdx.x >> 3);
    const int n = blk >> 3, d = blk & 7;
    const int g = n >> 3;
    const int bt = w;
    unsigned short* ts = tsb[w];

    // ---- X frags for this wave's bt (L2-resident in this XCD's slab)
    bf16x8 bx0 = *(const bf16x8*)(xbf + (size_t)n * 4096 + ((bt * 2 + 0) * 64 + l) * 8);
    bf16x8 bx1 = *(const bf16x8*)(xbf + (size_t)n * 4096 + ((bt * 2 + 1) * 64 + l) * 8);

    // ---- stage branch[n][k][d*64 .. +64): 16 KB fp32 -> 8.5 KB bf16 LDS.
    // 4 float4/thread; each k-row is a 256 B contiguous segment.
    {
        const float* bp = branch + (size_t)n * 32768 + d * 64;
        f32x4 stg[4];
        #pragma unroll
        for (int i = 0; i < 4; ++i) {
            const int fi = i * 256 + t;
            const int k = fi >> 4, c4 = (fi & 15) << 2;  // 16 float4 per row
            stg[i] = *(const f32x4*)(bp + (size_t)k * 512 + c4);
        }
        #pragma unroll
        for (int i = 0; i < 4; ++i) {
            const int fi = i * 256 + t;
            const int k = fi >> 4, c4 = (fi & 15) << 2;
            union { unsigned short h[4]; uint2 u; } q;
            q.h[0] = f2bf(stg[i][0]); q.h[1] = f2bf(stg[i][1]);
            q.h[2] = f2bf(stg[i][2]); q.h[3] = f2bf(stg[i][3]);
            *(uint2*)&brB[k * 68 + c4] = q.u;
        }
    }
    __syncthreads();

    // ---- pf: A-frags of S^T = Br[k][c] (row stride 34 words; l4 rows 8 apart
    // -> banks +16: worst 2-way, free)
    bf16x8 pf[4][2];
    #pragma unroll
    for (int cP = 0; cP < 4; ++cP)
        #pragma unroll
        for (int ks = 0; ks < 2; ++ks) {
            union { unsigned short h[8]; bf16x8 bv; } p;
            #pragma unroll
            for (int j = 0; j < 8; ++j)
                p.h[j] = brB[(32 * ks + 8 * l4 + j) * 68 + 16 * cP + l15];
            pf[cP][ks] = p.bv;
        }

    // ---- GEMM1^T for bt -> Ts -> GEMM2 (+ylg C-init) -> store
    float* outp = out + (size_t)(n * 8 + d) * 64;
    #pragma unroll
    for (int cP = 0; cP < 4; ++cP) {
        f32x4 s = {0.f, 0.f, 0.f, 0.f};
        s = __builtin_amdgcn_mfma_f32_16x16x32_bf16(pf[cP][0], bx0, s, 0, 0, 0);
        s = __builtin_amdgcn_mfma_f32_16x16x32_bf16(pf[cP][1], bx1, s, 0, 0, 0);
        union { unsigned short h[4]; uint2 u; } q;
        #pragma unroll
        for (int r = 0; r < 4; ++r) {
            float v = s[r];
            v = fmaxf(v, 0.2f * v);
            q.h[r] = f2bf(v);
        }
        *(uint2*)&ts[l15 * 72 + 16 * cP + 4 * l4] = q.u;
    }
    bf16x8 a20 = *(const bf16x8*)&ts[l15 * 72 + 8 * l4];
    bf16x8 a21 = *(const bf16x8*)&ts[l15 * 72 + 32 + 8 * l4];
    #pragma unroll
    for (int ft = 0; ft < 4; ++ft) {
        f32x4 o = *(const f32x4*)(ylg + (size_t)((g * 4 + bt) * 4 + ft) * 256 + l * 4);
        bf16x8 w30 = *(const bf16x8*)(w3f + (size_t)((ft * 2 + 0) * 64 + l) * 8);
        bf16x8 w31 = *(const bf16x8*)(w3f + (size_t)((ft * 2 + 1) * 64 + l) * 8);
        bf16x8 wf0 = *(const bf16x8*)(wsF + (size_t)((ft * 2 + 0) * 64 + l) * 8);
        bf16x8 wf1 = *(const bf16x8*)(wsF + (size_t)((ft * 2 + 1) * 64 + l) * 8);
        o = __builtin_amdgcn_mfma_f32_16x16x32_bf16(bx0, w30, o, 0, 0, 0);
        o = __builtin_amdgcn_mfma_f32_16x16x32_bf16(bx1, w31, o, 0, 0, 0);
        o = __builtin_amdgcn_mfma_f32_16x16x32_bf16(a20, wf0, o, 0, 0, 0);
        o = __builtin_amdgcn_mfma_f32_16x16x32_bf16(a21, wf1, o, 0, 0, 0);
        const float bv = bias[d * 64 + 16 * ft + l15];
        #pragma unroll
        for (int r = 0; r < 4; ++r) {
            float val = o[r] + bv;
            val = fmaxf(val, 0.2f * val);
            outp[(size_t)(16 * bt + 4 * l4 + r) * 262144 + 16 * ft + l15] = val;
        }
    }
}

extern "C" void kernel_launch(void* const* d_in, const int* in_sizes, int n_in,
                              void* d_out, int out_size, void* d_ws, size_t ws_size,
                              hipStream_t stream) {
    (void)in_sizes; (void)n_in; (void)out_size; (void)ws_size;
    const float* x0     = (const float*)d_in[0];
    const float* W0     = (const float*)d_in[1];
    const float* x1     = (const float*)d_in[2];
    const float* W1     = (const float*)d_in[3];
    const float* x2     = (const float*)d_in[4];
    const float* W2     = (const float*)d_in[5];
    const float* x3     = (const float*)d_in[6];
    const float* W3     = (const float*)d_in[7];
    const float* branch = (const float*)d_in[8];
    const float* Ws1    = (const float*)d_in[9];
    const float* Ws2    = (const float*)d_in[10];
    const float* bias   = (const float*)d_in[11];

    float* ylg          = (float*)d_ws;                                   // 1 MiB
    unsigned short* xbf = (unsigned short*)((char*)d_ws + 1048576);       // 4 MiB
    unsigned short* wsF = (unsigned short*)((char*)d_ws + 5242880);       // 8 KiB
    unsigned short* w3f = (unsigned short*)((char*)d_ws + 5251072);       // 8 KiB
    float* out = (float*)d_out;

    tree_prep<<<1601, 256, 0, stream>>>(x0, W0, x1, W1, x2, W2, x3, W3, Ws1, Ws2,
                                        ylg, xbf, wsF, w3f);
    tree_main<<<4096, 256, 0, stream>>>(branch, bias, ylg, xbf, wsF, w3f, out);
}